// Round 1
// baseline (48.637 us; speedup 1.0000x reference)
//
#include <hip/hip_runtime.h>

// out[b,n] = softmax-gated mix of 4 activations of s[b,n], gates from a
// per-neuron 4->4->4 MLP (W1,b1,W2,b2). All f32.
// Thread owns one neuron n (params in regs), loops over batch rows.

__global__ __launch_bounds__(256) void gatemix_kernel(
    const float* __restrict__ s,
    const float* __restrict__ W1,
    const float* __restrict__ b1,
    const float* __restrict__ W2,
    const float* __restrict__ b2,
    float* __restrict__ out,
    int B, int N, int bchunk)
{
    const int n = blockIdx.x * 256 + threadIdx.x;

    // Per-neuron params -> registers (float4 rows).
    // W1[n,k,j] at n*16 + k*4 + j : w1k = W1[n,k,:]
    // W2[n,j,k] at n*16 + j*4 + k : w2j = W2[n,j,:]
    const float4* W1v = (const float4*)W1;
    const float4* W2v = (const float4*)W2;
    const float4 w10 = W1v[n*4+0], w11 = W1v[n*4+1], w12 = W1v[n*4+2], w13 = W1v[n*4+3];
    const float4 w20 = W2v[n*4+0], w21 = W2v[n*4+1], w22 = W2v[n*4+2], w23 = W2v[n*4+3];
    const float4 c1 = ((const float4*)b1)[n];
    const float4 c2 = ((const float4*)b2)[n];

    const float L2E = 1.44269504088896340736f; // log2(e)

    const int b0 = blockIdx.y * bchunk;
    const int bend = b0 + bchunk;

    #pragma unroll 4
    for (int b = b0; b < bend; ++b) {
        const size_t idx = (size_t)b * N + n;
        const float x = s[idx];

        // acts: relu, sigmoid, antirelu, identity
        const float a0 = fmaxf(x, 0.0f);
        const float a2 = fminf(x, 0.0f);
        const float a3 = x;
        const float a1 = __builtin_amdgcn_rcpf(1.0f + __builtin_amdgcn_exp2f(-x * L2E));

        // h_j = sigmoid( b1[j] + sum_k a_k * W1[n,k,j] )
        float h0 = fmaf(a0, w10.x, fmaf(a1, w11.x, fmaf(a2, w12.x, fmaf(a3, w13.x, c1.x))));
        float h1 = fmaf(a0, w10.y, fmaf(a1, w11.y, fmaf(a2, w12.y, fmaf(a3, w13.y, c1.y))));
        float h2 = fmaf(a0, w10.z, fmaf(a1, w11.z, fmaf(a2, w12.z, fmaf(a3, w13.z, c1.z))));
        float h3 = fmaf(a0, w10.w, fmaf(a1, w11.w, fmaf(a2, w12.w, fmaf(a3, w13.w, c1.w))));
        h0 = __builtin_amdgcn_rcpf(1.0f + __builtin_amdgcn_exp2f(-h0 * L2E));
        h1 = __builtin_amdgcn_rcpf(1.0f + __builtin_amdgcn_exp2f(-h1 * L2E));
        h2 = __builtin_amdgcn_rcpf(1.0f + __builtin_amdgcn_exp2f(-h2 * L2E));
        h3 = __builtin_amdgcn_rcpf(1.0f + __builtin_amdgcn_exp2f(-h3 * L2E));

        // logits_k = b2[k] + sum_j h_j * W2[n,j,k]
        const float l0 = fmaf(h0, w20.x, fmaf(h1, w21.x, fmaf(h2, w22.x, fmaf(h3, w23.x, c2.x))));
        const float l1 = fmaf(h0, w20.y, fmaf(h1, w21.y, fmaf(h2, w22.y, fmaf(h3, w23.y, c2.y))));
        const float l2 = fmaf(h0, w20.z, fmaf(h1, w21.z, fmaf(h2, w22.z, fmaf(h3, w23.z, c2.z))));
        const float l3 = fmaf(h0, w20.w, fmaf(h1, w21.w, fmaf(h2, w22.w, fmaf(h3, w23.w, c2.w))));

        // softmax (logits bounded in [-2.5,2.5] -> no max-subtraction needed)
        const float e0 = __builtin_amdgcn_exp2f(l0 * L2E);
        const float e1 = __builtin_amdgcn_exp2f(l1 * L2E);
        const float e2 = __builtin_amdgcn_exp2f(l2 * L2E);
        const float e3 = __builtin_amdgcn_exp2f(l3 * L2E);
        const float den = (e0 + e1) + (e2 + e3);
        const float num = fmaf(e0, a0, fmaf(e1, a1, fmaf(e2, a2, e3 * a3)));

        out[idx] = num * __builtin_amdgcn_rcpf(den);
    }
}

extern "C" void kernel_launch(void* const* d_in, const int* in_sizes, int n_in,
                              void* d_out, int out_size, void* d_ws, size_t ws_size,
                              hipStream_t stream) {
    const float* s  = (const float*)d_in[0];
    const float* W1 = (const float*)d_in[1];
    const float* b1 = (const float*)d_in[2];
    const float* W2 = (const float*)d_in[3];
    const float* b2 = (const float*)d_in[4];
    float* out = (float*)d_out;

    const int K = 4;
    const int N = in_sizes[2] / K;       // b1 is N*K
    const int B = in_sizes[0] / N;       // s is B*N

    const int bchunk = 32;               // rows per block
    dim3 grid(N / 256, B / bchunk);
    gatemix_kernel<<<grid, 256, 0, stream>>>(s, W1, b1, W2, b2, out, B, N, bchunk);
}